// Round 1
// baseline (846.905 us; speedup 1.0000x reference)
//
#include <hip/hip_runtime.h>
#include <hip/hip_bf16.h>
#include <math.h>

using frag8 = __attribute__((ext_vector_type(8))) short;
using f32x4 = __attribute__((ext_vector_type(4))) float;

#define BM 128
#define BN 128
#define BK 32

typedef const __attribute__((address_space(1))) unsigned char glb_u8;
typedef __attribute__((address_space(3))) unsigned char lds_u8;

__device__ __forceinline__ float b2f(unsigned short v) {
    union { unsigned u; float f; } x; x.u = ((unsigned)v) << 16; return x.f;
}
__device__ __forceinline__ unsigned short f2b(float f) {
    union { float f; unsigned u; } x; x.f = f;
    unsigned u = x.u;
    u += 0x7fffu + ((u >> 16) & 1u);   // RNE
    return (unsigned short)(u >> 16);
}

// ---------------- cast fp32 -> bf16 (vectorized) ----------------
__global__ __launch_bounds__(256) void cast_kernel(const float* __restrict__ in,
                                                   unsigned short* __restrict__ out, long n) {
    long i = ((long)blockIdx.x * 256 + threadIdx.x) * 8;
    if (i >= n) return;
    float4 a = *(const float4*)(in + i);
    float4 b = *(const float4*)(in + i + 4);
    struct alignas(16) U8 { unsigned short s[8]; } o;
    o.s[0] = f2b(a.x); o.s[1] = f2b(a.y); o.s[2] = f2b(a.z); o.s[3] = f2b(a.w);
    o.s[4] = f2b(b.x); o.s[5] = f2b(b.y); o.s[6] = f2b(b.z); o.s[7] = f2b(b.w);
    *(U8*)(out + i) = o;
}

// ---------------- transpose + cast: in (R x C) fp32 -> out (C x R) bf16 ----------------
__global__ void transpose_cast(const float* __restrict__ in, unsigned short* __restrict__ out,
                               int R, int Ccols) {
    __shared__ float tile[32][33];
    int bx = blockIdx.x * 32;   // col base in input
    int by = blockIdx.y * 32;   // row base in input
    int tx = threadIdx.x, ty = threadIdx.y;
    for (int r = ty; r < 32; r += 8)
        tile[r][tx] = in[(size_t)(by + r) * Ccols + bx + tx];
    __syncthreads();
    for (int r = ty; r < 32; r += 8)
        out[(size_t)(bx + r) * R + by + tx] = f2b(tile[tx][r]);
}

// ---------------- bf16 MFMA GEMM: C[M,N] = A[M,K] * Bt[N,K]^T ----------------
// mode 0: store fp32 to Cf
// mode 1: split epilogue -> V=gelu, Q=gelu, Lam=lb+(1-lb)*sigmoid  (N must be 3072)
__global__ __launch_bounds__(256) void gemm_bf16(
    const unsigned short* __restrict__ A, const unsigned short* __restrict__ Bt,
    int M, int N, int K, int mode,
    float* __restrict__ Cf,
    unsigned short* __restrict__ Vp, unsigned short* __restrict__ Qp,
    unsigned short* __restrict__ Lp, const float* __restrict__ lb) {
    __shared__ __align__(16) unsigned short sA[BM * BK];
    __shared__ __align__(16) unsigned short sB[BN * BK];
    const int tid = threadIdx.x;
    const int lane16 = tid & 15;
    const int quad = (tid & 63) >> 4;
    const int wave = tid >> 6;
    const int wm = (wave >> 1) * 64;
    const int wn = (wave & 1) * 64;
    const long m0 = (long)blockIdx.y * BM;
    const long n0 = (long)blockIdx.x * BN;

    const int off0 = tid * 16;            // byte offset within 8KB tile
    const int row0 = off0 >> 6, kb0 = off0 & 63;
    const int off1 = off0 + 4096;
    const int row1 = off1 >> 6, kb1 = off1 & 63;

    const char* Ab = (const char*)A + m0 * K * 2;
    const char* Bb = (const char*)Bt + n0 * K * 2;

    f32x4 acc[4][4];
#pragma unroll
    for (int i = 0; i < 4; ++i)
#pragma unroll
        for (int j = 0; j < 4; ++j) acc[i][j] = (f32x4){0.f, 0.f, 0.f, 0.f};

    for (int kt = 0; kt < K; kt += BK) {
        __syncthreads();
        __builtin_amdgcn_global_load_lds((glb_u8*)(Ab + (long)row0 * K * 2 + (long)kt * 2 + kb0),
                                         (lds_u8*)((char*)sA + off0), 16, 0, 0);
        __builtin_amdgcn_global_load_lds((glb_u8*)(Ab + (long)row1 * K * 2 + (long)kt * 2 + kb1),
                                         (lds_u8*)((char*)sA + off1), 16, 0, 0);
        __builtin_amdgcn_global_load_lds((glb_u8*)(Bb + (long)row0 * K * 2 + (long)kt * 2 + kb0),
                                         (lds_u8*)((char*)sB + off0), 16, 0, 0);
        __builtin_amdgcn_global_load_lds((glb_u8*)(Bb + (long)row1 * K * 2 + (long)kt * 2 + kb1),
                                         (lds_u8*)((char*)sB + off1), 16, 0, 0);
        __syncthreads();

        frag8 af[4], bfr[4];
#pragma unroll
        for (int mf = 0; mf < 4; ++mf)
            af[mf] = *(const frag8*)(sA + (wm + mf * 16 + lane16) * BK + quad * 8);
#pragma unroll
        for (int nf = 0; nf < 4; ++nf)
            bfr[nf] = *(const frag8*)(sB + (wn + nf * 16 + lane16) * BK + quad * 8);
#pragma unroll
        for (int mf = 0; mf < 4; ++mf)
#pragma unroll
            for (int nf = 0; nf < 4; ++nf)
                acc[mf][nf] = __builtin_amdgcn_mfma_f32_16x16x32_bf16(af[mf], bfr[nf], acc[mf][nf], 0, 0, 0);
    }

#pragma unroll
    for (int mf = 0; mf < 4; ++mf) {
#pragma unroll
        for (int nf = 0; nf < 4; ++nf) {
            long col = n0 + wn + nf * 16 + lane16;
#pragma unroll
            for (int r = 0; r < 4; ++r) {
                long row = m0 + wm + mf * 16 + quad * 4 + r;
                float v = acc[mf][nf][r];
                if (mode == 0) {
                    Cf[row * N + col] = v;
                } else {
                    if (col < 1024) {
                        float g = 0.5f * v * (1.0f + erff(v * 0.70710678118f));
                        Vp[row * 1024 + col] = f2b(g);
                    } else if (col < 2048) {
                        float g = 0.5f * v * (1.0f + erff(v * 0.70710678118f));
                        Qp[row * 1024 + (col - 1024)] = f2b(g);
                    } else {
                        float sg = 1.0f / (1.0f + __expf(-v));
                        float l = lb[col - 2048];
                        Lp[row * 1024 + (col - 2048)] = f2b(l + (1.0f - l) * sg);
                    }
                }
            }
        }
    }
}

// ---------------- scan phase 1: per-(chain,chunk) local state + decay product ----------------
// chain = bi*512 + h  (bi in [0,8), h in [0,512)); arrays are (32768, 1024) bf16, row = t*8+bi
__global__ __launch_bounds__(256) void scan_phase1(
    const unsigned short* __restrict__ lam, const unsigned short* __restrict__ V,
    float* __restrict__ Sl, float* __restrict__ P, int L) {
    int cid = blockIdx.x * 256 + threadIdx.x;  // 0..4095
    int c = blockIdx.y;
    int bi = cid >> 9, h = cid & 511;
    float s00 = 0, s01 = 0, s10 = 0, s11 = 0, p0 = 1.f, p1 = 1.f;
    int t0 = c * L;
    const unsigned* lamp = (const unsigned*)lam;
    const unsigned* vp = (const unsigned*)V;
    for (int t = t0; t < t0 + L; ++t) {
        long idx = (long)(t * 8 + bi) * 512 + h;
        unsigned lu = lamp[idx], vu = vp[idx];
        float la0 = b2f((unsigned short)lu), la1 = b2f((unsigned short)(lu >> 16));
        float v0 = b2f((unsigned short)vu), v1 = b2f((unsigned short)(vu >> 16));
        float k0 = 1.f - la0, k1 = 1.f - la1;
        s00 = fmaf(la0, s00, k0 * v0); s01 = fmaf(la0, s01, k0 * v1);
        s10 = fmaf(la1, s10, k1 * v0); s11 = fmaf(la1, s11, k1 * v1);
        p0 *= la0; p1 *= la1;
    }
    long base = (long)c * 4096 + cid;
    ((float4*)Sl)[base] = make_float4(s00, s01, s10, s11);
    ((float2*)P)[base] = make_float2(p0, p1);
}

// ---------------- scan phase 2: sequential combine over chunks ----------------
__global__ __launch_bounds__(256) void scan_phase2(
    const float* __restrict__ Sl, const float* __restrict__ P,
    float* __restrict__ Sini, int C) {
    int idx = blockIdx.x * 256 + threadIdx.x;  // 0..16383
    int cid = idx >> 2, ij = idx & 3, i = (idx >> 1) & 1;
    float s = 0.f;
    for (int c = 0; c < C; ++c) {
        long base = (long)c * 4096 + cid;
        Sini[base * 4 + ij] = s;
        s = fmaf(P[base * 2 + i], s, Sl[base * 4 + ij]);
    }
}

// ---------------- scan phase 3: replay with seeded state, emit o ----------------
__global__ __launch_bounds__(256) void scan_phase3(
    const unsigned short* __restrict__ lam, const unsigned short* __restrict__ V,
    const unsigned short* __restrict__ Q, const float* __restrict__ Sini,
    unsigned short* __restrict__ o, int L) {
    int cid = blockIdx.x * 256 + threadIdx.x;
    int c = blockIdx.y;
    int bi = cid >> 9, h = cid & 511;
    float4 si = ((const float4*)Sini)[(long)c * 4096 + cid];
    float s00 = si.x, s01 = si.y, s10 = si.z, s11 = si.w;
    int t0 = c * L;
    const unsigned* lamp = (const unsigned*)lam;
    const unsigned* vp = (const unsigned*)V;
    const unsigned* qp = (const unsigned*)Q;
    unsigned* op = (unsigned*)o;
    for (int t = t0; t < t0 + L; ++t) {
        long idx = (long)(t * 8 + bi) * 512 + h;
        unsigned lu = lamp[idx], vu = vp[idx], qu = qp[idx];
        float la0 = b2f((unsigned short)lu), la1 = b2f((unsigned short)(lu >> 16));
        float v0 = b2f((unsigned short)vu), v1 = b2f((unsigned short)(vu >> 16));
        float q0 = b2f((unsigned short)qu), q1 = b2f((unsigned short)(qu >> 16));
        float k0 = 1.f - la0, k1 = 1.f - la1;
        s00 = fmaf(la0, s00, k0 * v0); s01 = fmaf(la0, s01, k0 * v1);
        s10 = fmaf(la1, s10, k1 * v0); s11 = fmaf(la1, s11, k1 * v1);
        float o0 = q0 * s00 + q1 * s10;
        float o1 = q0 * s01 + q1 * s11;
        op[idx] = (unsigned)f2b(o0) | ((unsigned)f2b(o1) << 16);
    }
}

extern "C" void kernel_launch(void* const* d_in, const int* in_sizes, int n_in,
                              void* d_out, int out_size, void* d_ws, size_t ws_size,
                              hipStream_t stream) {
    const float* x = (const float*)d_in[0];
    const float* lb = (const float*)d_in[1];
    const float* W_in = (const float*)d_in[2];
    const float* W_out = (const float*)d_in[3];
    float* out = (float*)d_out;

    const int n = 4096, b = 8, d = 1024;
    const long NB = (long)n * b;   // 32768 rows
    const int C = 64, L = 64;      // chunks x chunk length (C*L == n)

    char* ws = (char*)d_ws;
    size_t off = 0;
    auto alloc = [&](size_t bytes) -> char* {
        char* p = ws + off;
        off += (bytes + 255) & ~(size_t)255;
        return p;
    };
    unsigned short* xb   = (unsigned short*)alloc(NB * d * 2);          // reused as o after GEMM1
    unsigned short* Wint = (unsigned short*)alloc((size_t)3 * d * d * 2);
    unsigned short* Wot  = (unsigned short*)alloc((size_t)d * d * 2);
    unsigned short* Vb   = (unsigned short*)alloc(NB * d * 2);
    unsigned short* Qb   = (unsigned short*)alloc(NB * d * 2);
    unsigned short* Lb   = (unsigned short*)alloc(NB * d * 2);
    float* Sl   = (float*)alloc((size_t)C * 4096 * 4 * 4);
    float* P    = (float*)alloc((size_t)C * 4096 * 2 * 4);
    float* Sini = (float*)alloc((size_t)C * 4096 * 4 * 4);

    // 1) cast x -> bf16
    cast_kernel<<<dim3((unsigned)((NB * d) / (256 * 8))), 256, 0, stream>>>(x, xb, NB * d);
    // 2) transpose+cast weights (so GEMM B operand is K-contiguous)
    transpose_cast<<<dim3(3 * d / 32, d / 32), dim3(32, 8), 0, stream>>>(W_in, Wint, d, 3 * d);
    transpose_cast<<<dim3(d / 32, d / 32), dim3(32, 8), 0, stream>>>(W_out, Wot, d, d);
    // 3) GEMM1 + fused activations -> V, Q, lam (bf16)
    gemm_bf16<<<dim3(3 * d / BN, (unsigned)(NB / BM)), 256, 0, stream>>>(
        xb, Wint, (int)NB, 3 * d, d, 1, nullptr, Vb, Qb, Lb, lb);
    // 4) chunked scan
    scan_phase1<<<dim3(16, C), 256, 0, stream>>>(Lb, Vb, Sl, P, L);
    scan_phase2<<<dim3(64), 256, 0, stream>>>(Sl, P, Sini, C);
    unsigned short* ob = xb;  // xb dead after GEMM1; reuse as o
    scan_phase3<<<dim3(16, C), 256, 0, stream>>>(Lb, Vb, Qb, Sini, ob, L);
    // 5) GEMM2 -> fp32 output
    gemm_bf16<<<dim3(d / BN, (unsigned)(NB / BM)), 256, 0, stream>>>(
        ob, Wot, (int)NB, d, d, 0, out, nullptr, nullptr, nullptr, nullptr);
}

// Round 2
// 790.427 us; speedup vs baseline: 1.0715x; 1.0715x over previous
//
#include <hip/hip_runtime.h>
#include <hip/hip_bf16.h>
#include <math.h>

using frag8 = __attribute__((ext_vector_type(8))) short;
using f32x4 = __attribute__((ext_vector_type(4))) float;

#define BM 128
#define BN 128
#define BK 64

typedef const __attribute__((address_space(1))) unsigned char glb_u8;
typedef __attribute__((address_space(3))) unsigned char lds_u8;

__device__ __forceinline__ float b2f(unsigned short v) {
    union { unsigned u; float f; } x; x.u = ((unsigned)v) << 16; return x.f;
}
__device__ __forceinline__ unsigned short f2b(float f) {
    union { float f; unsigned u; } x; x.f = f;
    unsigned u = x.u;
    u += 0x7fffu + ((u >> 16) & 1u);   // RNE
    return (unsigned short)(u >> 16);
}

// ---------------- cast fp32 -> bf16 (vectorized) ----------------
__global__ __launch_bounds__(256) void cast_kernel(const float* __restrict__ in,
                                                   unsigned short* __restrict__ out, long n) {
    long i = ((long)blockIdx.x * 256 + threadIdx.x) * 8;
    if (i >= n) return;
    float4 a = *(const float4*)(in + i);
    float4 b = *(const float4*)(in + i + 4);
    struct alignas(16) U8 { unsigned short s[8]; } o;
    o.s[0] = f2b(a.x); o.s[1] = f2b(a.y); o.s[2] = f2b(a.z); o.s[3] = f2b(a.w);
    o.s[4] = f2b(b.x); o.s[5] = f2b(b.y); o.s[6] = f2b(b.z); o.s[7] = f2b(b.w);
    *(U8*)(out + i) = o;
}

// ---------------- transpose + cast: in (R x C) fp32 -> out (C x R) bf16 ----------------
__global__ void transpose_cast(const float* __restrict__ in, unsigned short* __restrict__ out,
                               int R, int Ccols) {
    __shared__ float tile[32][33];
    int bx = blockIdx.x * 32;   // col base in input
    int by = blockIdx.y * 32;   // row base in input
    int tx = threadIdx.x, ty = threadIdx.y;
    for (int r = ty; r < 32; r += 8)
        tile[r][tx] = in[(size_t)(by + r) * Ccols + bx + tx];
    __syncthreads();
    for (int r = ty; r < 32; r += 8)
        out[(size_t)(bx + r) * R + by + tx] = f2b(tile[tx][r]);
}

// ---------------- bf16 MFMA GEMM: C[M,N] = A[M,K] * Bt[N,K]^T ----------------
// LDS tiles are XOR-swizzled at 16B-chunk granularity (chunk' = chunk ^ (row&7)):
// global_load_lds forces dest = base + lane*16, so we permute the *source* chunk
// per lane instead; read side applies the same XOR. Breaks the 8..16-way bank
// aliasing of row-major [row][BK] tiles down to 2-way (free per m136).
// mode 0: store fp32 to Cf
// mode 1: N==3072 split epilogue (block-uniform segment): V=gelu, Q=gelu,
//         Lam=lb+(1-lb)*sigmoid, all bf16.
__global__ __launch_bounds__(256) void gemm_bf16(
    const unsigned short* __restrict__ A, const unsigned short* __restrict__ Bt,
    int M, int N, int K, int mode,
    float* __restrict__ Cf,
    unsigned short* __restrict__ Vp, unsigned short* __restrict__ Qp,
    unsigned short* __restrict__ Lp, const float* __restrict__ lb) {
    __shared__ __align__(16) unsigned short sA[BM * BK];   // 16 KB
    __shared__ __align__(16) unsigned short sB[BN * BK];   // 16 KB
    const int tid = threadIdx.x;
    const int lane16 = tid & 15;
    const int quad = (tid & 63) >> 4;
    const int wave = tid >> 6;
    const int wm = (wave >> 1) * 64;
    const int wn = (wave & 1) * 64;
    const long m0 = (long)blockIdx.y * BM;
    const long n0 = (long)blockIdx.x * BN;
    const long K2 = (long)K * 2;

    // staging: round p covers LDS bytes [p*4096 + tid*16, +16)
    long srcA[4], srcB[4];
    int ldsOff[4];
#pragma unroll
    for (int p = 0; p < 4; ++p) {
        int off = p * 4096 + tid * 16;
        int r = off >> 7;              // row (128 B per row)
        int c = (off >> 4) & 7;        // chunk within row
        int sc = c ^ (r & 7);          // swizzled source chunk
        ldsOff[p] = off;
        srcA[p] = (long)r * K2 + (long)sc * 16;
        srcB[p] = srcA[p];
    }
    const char* Ab = (const char*)A + m0 * K2;
    const char* Bb = (const char*)Bt + n0 * K2;

    // LDS fragment read offsets (ushort index), constant across K-loop
    int ldsA[2][4], ldsB[2][4];
#pragma unroll
    for (int mf = 0; mf < 4; ++mf) {
        int rowA = wm + mf * 16 + lane16;
        int rowB = wn + mf * 16 + lane16;
#pragma unroll
        for (int ks = 0; ks < 2; ++ks) {
            int j = quad + 4 * ks;
            ldsA[ks][mf] = rowA * 64 + ((j ^ (rowA & 7)) * 8);
            ldsB[ks][mf] = rowB * 64 + ((j ^ (rowB & 7)) * 8);
        }
    }

    f32x4 acc[4][4];
#pragma unroll
    for (int i = 0; i < 4; ++i)
#pragma unroll
        for (int j = 0; j < 4; ++j) acc[i][j] = (f32x4){0.f, 0.f, 0.f, 0.f};

    for (int kt = 0; kt < K; kt += BK) {
        __syncthreads();
        long kb = (long)kt * 2;
#pragma unroll
        for (int p = 0; p < 4; ++p)
            __builtin_amdgcn_global_load_lds((glb_u8*)(Ab + srcA[p] + kb),
                                             (lds_u8*)((char*)sA + ldsOff[p]), 16, 0, 0);
#pragma unroll
        for (int p = 0; p < 4; ++p)
            __builtin_amdgcn_global_load_lds((glb_u8*)(Bb + srcB[p] + kb),
                                             (lds_u8*)((char*)sB + ldsOff[p]), 16, 0, 0);
        __syncthreads();

#pragma unroll
        for (int ks = 0; ks < 2; ++ks) {
            frag8 af[4], bfr[4];
#pragma unroll
            for (int mf = 0; mf < 4; ++mf) af[mf] = *(const frag8*)(sA + ldsA[ks][mf]);
#pragma unroll
            for (int nf = 0; nf < 4; ++nf) bfr[nf] = *(const frag8*)(sB + ldsB[ks][nf]);
#pragma unroll
            for (int mf = 0; mf < 4; ++mf)
#pragma unroll
                for (int nf = 0; nf < 4; ++nf)
                    acc[mf][nf] = __builtin_amdgcn_mfma_f32_16x16x32_bf16(af[mf], bfr[nf], acc[mf][nf], 0, 0, 0);
        }
    }

    if (mode == 0) {
#pragma unroll
        for (int mf = 0; mf < 4; ++mf)
#pragma unroll
            for (int nf = 0; nf < 4; ++nf) {
                long col = n0 + wn + nf * 16 + lane16;
#pragma unroll
                for (int r = 0; r < 4; ++r) {
                    long row = m0 + wm + mf * 16 + quad * 4 + r;
                    Cf[row * N + col] = acc[mf][nf][r];
                }
            }
    } else {
        // block-uniform segment: BN=128 divides 1024, so each block is in one segment
        const int seg = (int)(n0 >> 10);            // 0=V, 1=Q, 2=Lam
        const int cbase = (int)(n0 & 1023) + wn;
        unsigned short* dst = (seg == 0) ? Vp : (seg == 1 ? Qp : Lp);
#pragma unroll
        for (int mf = 0; mf < 4; ++mf)
#pragma unroll
            for (int nf = 0; nf < 4; ++nf) {
                int col = cbase + nf * 16 + lane16;
#pragma unroll
                for (int r = 0; r < 4; ++r) {
                    long row = m0 + wm + mf * 16 + quad * 4 + r;
                    float v = acc[mf][nf][r];
                    float res;
                    if (seg < 2) {
                        // tanh-form gelu: x * sigmoid(1.5958*x*(1+0.044715 x^2))
                        float u = 1.59576912f * v * (1.0f + 0.044715f * v * v);
                        res = v / (1.0f + __expf(-u));
                    } else {
                        float sg = 1.0f / (1.0f + __expf(-v));
                        float l = lb[col];
                        res = l + (1.0f - l) * sg;
                    }
                    dst[row * 1024 + col] = f2b(res);
                }
            }
    }
}

// ---------------- scan phase 1: per-(chain,chunk) local state + decay product ----------------
__global__ __launch_bounds__(256) void scan_phase1(
    const unsigned short* __restrict__ lam, const unsigned short* __restrict__ V,
    float* __restrict__ Sl, float* __restrict__ P, int L) {
    int cid = blockIdx.x * 256 + threadIdx.x;  // 0..4095
    int c = blockIdx.y;
    int bi = cid >> 9, h = cid & 511;
    float s00 = 0, s01 = 0, s10 = 0, s11 = 0, p0 = 1.f, p1 = 1.f;
    int t0 = c * L;
    const unsigned* lamp = (const unsigned*)lam;
    const unsigned* vp = (const unsigned*)V;
    for (int t = t0; t < t0 + L; ++t) {
        long idx = (long)(t * 8 + bi) * 512 + h;
        unsigned lu = lamp[idx], vu = vp[idx];
        float la0 = b2f((unsigned short)lu), la1 = b2f((unsigned short)(lu >> 16));
        float v0 = b2f((unsigned short)vu), v1 = b2f((unsigned short)(vu >> 16));
        float k0 = 1.f - la0, k1 = 1.f - la1;
        s00 = fmaf(la0, s00, k0 * v0); s01 = fmaf(la0, s01, k0 * v1);
        s10 = fmaf(la1, s10, k1 * v0); s11 = fmaf(la1, s11, k1 * v1);
        p0 *= la0; p1 *= la1;
    }
    long base = (long)c * 4096 + cid;
    ((float4*)Sl)[base] = make_float4(s00, s01, s10, s11);
    ((float2*)P)[base] = make_float2(p0, p1);
}

// ---------------- scan phase 2: sequential combine over chunks ----------------
__global__ __launch_bounds__(256) void scan_phase2(
    const float* __restrict__ Sl, const float* __restrict__ P,
    float* __restrict__ Sini, int C) {
    int idx = blockIdx.x * 256 + threadIdx.x;  // 0..16383
    int cid = idx >> 2, ij = idx & 3, i = (idx >> 1) & 1;
    float s = 0.f;
    for (int c = 0; c < C; ++c) {
        long base = (long)c * 4096 + cid;
        Sini[base * 4 + ij] = s;
        s = fmaf(P[base * 2 + i], s, Sl[base * 4 + ij]);
    }
}

// ---------------- scan phase 3: replay with seeded state, emit o ----------------
__global__ __launch_bounds__(256) void scan_phase3(
    const unsigned short* __restrict__ lam, const unsigned short* __restrict__ V,
    const unsigned short* __restrict__ Q, const float* __restrict__ Sini,
    unsigned short* __restrict__ o, int L) {
    int cid = blockIdx.x * 256 + threadIdx.x;
    int c = blockIdx.y;
    int bi = cid >> 9, h = cid & 511;
    float4 si = ((const float4*)Sini)[(long)c * 4096 + cid];
    float s00 = si.x, s01 = si.y, s10 = si.z, s11 = si.w;
    int t0 = c * L;
    const unsigned* lamp = (const unsigned*)lam;
    const unsigned* vp = (const unsigned*)V;
    const unsigned* qp = (const unsigned*)Q;
    unsigned* op = (unsigned*)o;
    for (int t = t0; t < t0 + L; ++t) {
        long idx = (long)(t * 8 + bi) * 512 + h;
        unsigned lu = lamp[idx], vu = vp[idx], qu = qp[idx];
        float la0 = b2f((unsigned short)lu), la1 = b2f((unsigned short)(lu >> 16));
        float v0 = b2f((unsigned short)vu), v1 = b2f((unsigned short)(vu >> 16));
        float q0 = b2f((unsigned short)qu), q1 = b2f((unsigned short)(qu >> 16));
        float k0 = 1.f - la0, k1 = 1.f - la1;
        s00 = fmaf(la0, s00, k0 * v0); s01 = fmaf(la0, s01, k0 * v1);
        s10 = fmaf(la1, s10, k1 * v0); s11 = fmaf(la1, s11, k1 * v1);
        float o0 = q0 * s00 + q1 * s10;
        float o1 = q0 * s01 + q1 * s11;
        op[idx] = (unsigned)f2b(o0) | ((unsigned)f2b(o1) << 16);
    }
}

extern "C" void kernel_launch(void* const* d_in, const int* in_sizes, int n_in,
                              void* d_out, int out_size, void* d_ws, size_t ws_size,
                              hipStream_t stream) {
    const float* x = (const float*)d_in[0];
    const float* lb = (const float*)d_in[1];
    const float* W_in = (const float*)d_in[2];
    const float* W_out = (const float*)d_in[3];
    float* out = (float*)d_out;

    const int n = 4096, b = 8, d = 1024;
    const long NB = (long)n * b;   // 32768 rows
    const int C = 64, L = 64;      // chunks x chunk length (C*L == n)

    char* ws = (char*)d_ws;
    size_t off = 0;
    auto alloc = [&](size_t bytes) -> char* {
        char* p = ws + off;
        off += (bytes + 255) & ~(size_t)255;
        return p;
    };
    unsigned short* xb   = (unsigned short*)alloc(NB * d * 2);          // reused as o after GEMM1
    unsigned short* Wint = (unsigned short*)alloc((size_t)3 * d * d * 2);
    unsigned short* Wot  = (unsigned short*)alloc((size_t)d * d * 2);
    unsigned short* Vb   = (unsigned short*)alloc(NB * d * 2);
    unsigned short* Qb   = (unsigned short*)alloc(NB * d * 2);
    unsigned short* Lb   = (unsigned short*)alloc(NB * d * 2);
    float* Sl   = (float*)alloc((size_t)C * 4096 * 4 * 4);
    float* P    = (float*)alloc((size_t)C * 4096 * 2 * 4);
    float* Sini = (float*)alloc((size_t)C * 4096 * 4 * 4);

    // 1) cast x -> bf16
    cast_kernel<<<dim3((unsigned)((NB * d) / (256 * 8))), 256, 0, stream>>>(x, xb, NB * d);
    // 2) transpose+cast weights (so GEMM B operand is K-contiguous)
    transpose_cast<<<dim3(3 * d / 32, d / 32), dim3(32, 8), 0, stream>>>(W_in, Wint, d, 3 * d);
    transpose_cast<<<dim3(d / 32, d / 32), dim3(32, 8), 0, stream>>>(W_out, Wot, d, d);
    // 3) GEMM1 + fused activations -> V, Q, lam (bf16)
    gemm_bf16<<<dim3(3 * d / BN, (unsigned)(NB / BM)), 256, 0, stream>>>(
        xb, Wint, (int)NB, 3 * d, d, 1, nullptr, Vb, Qb, Lb, lb);
    // 4) chunked scan
    scan_phase1<<<dim3(16, C), 256, 0, stream>>>(Lb, Vb, Sl, P, L);
    scan_phase2<<<dim3(64), 256, 0, stream>>>(Sl, P, Sini, C);
    unsigned short* ob = xb;  // xb dead after GEMM1; reuse as o
    scan_phase3<<<dim3(16, C), 256, 0, stream>>>(Lb, Vb, Qb, Sini, ob, L);
    // 5) GEMM2 -> fp32 output
    gemm_bf16<<<dim3(d / BN, (unsigned)(NB / BM)), 256, 0, stream>>>(
        ob, Wot, (int)NB, d, d, 0, out, nullptr, nullptr, nullptr, nullptr);
}